// Round 10
// baseline (147.404 us; speedup 1.0000x reference)
//
#include <hip/hip_runtime.h>
#include <math.h>

#define DM 256
#define LSEQ 2048
#define BATCH 8
#define NLAYER 8
#define EMAX 192
#define LN_EPS 1e-5f
#define BM 32
#define BLKS 64                     // blocks per batch
#define NPROD 7                     // producer blocks per batch (rows t<=192)
#define TAILB 57                    // first tail block (rows u<=192)

// LDS layout (bytes): Ah [32 rows][512 B, XOR-swizzled] @0 ; Al @16384 ; red @32768
#define AL_OFF   16384
#define RED_OFF  32768              // red [32 rows][10] f32
#define SMEM_SZ  (RED_OFF + 1280)   // 34048 B

typedef float f32x4 __attribute__((ext_vector_type(4)));
typedef short bf16x8 __attribute__((ext_vector_type(8)));
typedef unsigned short u16;
typedef unsigned short u16x8 __attribute__((ext_vector_type(8)));

union V8 { u16x8 u; bf16x8 b; };

// branch-free erf, Abramowitz-Stegun 7.1.26, |err| <= 1.5e-7
__device__ __forceinline__ float erf_fast(float x) {
    float ax = fabsf(x);
    float t = __builtin_amdgcn_rcpf(fmaf(0.3275911f, ax, 1.f));
    float p = fmaf(t, 1.061405429f, -1.453152027f);
    p = fmaf(t, p, 1.421413741f);
    p = fmaf(t, p, -0.284496736f);
    p = fmaf(t, p, 0.254829592f);
    p = p * t;
    float e = __expf(-ax * ax);
    float r = 1.f - p * e;
    return copysignf(r, x);
}

__device__ __forceinline__ float gelu_fast(float v) {
    return 0.5f * v * (1.f + erf_fast(v * 0.70710678118654752f));
}

// split fp32 -> bf16 hi (truncated, exact-subtractable) + bf16 lo (RNE of remainder)
__device__ __forceinline__ void split2(float g, u16& hi, u16& lo) {
    unsigned u = __float_as_uint(g);
    hi = (u16)(u >> 16);
    float fh = __uint_as_float(u & 0xFFFF0000u);
    float r = g - fh;
    unsigned v = __float_as_uint(r);
    v = v + 0x7FFFu + ((v >> 16) & 1u);
    lo = (u16)(v >> 16);
}

// scatter one element into the swizzled A layout (matches MFMA read mapping, verified r5-r9)
__device__ __forceinline__ void writeA(char* smem, int row, int col, u16 hi, u16 lo) {
    int aby = row * 512 + (((col >> 3) ^ (row & 7)) << 4) + (col & 7) * 2;
    *(u16*)(smem + aby) = hi;
    *(u16*)(smem + AL_OFF + aby) = lo;
}

// ---------------- merged prep: blocks 0..255 = pW split+pack; 256..263 = prep0 ----------------
__global__ void k_prep(const float* __restrict__ pW, u16* __restrict__ pWh,
                       u16* __restrict__ pWl,
                       const float* __restrict__ x, const float* __restrict__ inW,
                       const float* __restrict__ inb, const float* __restrict__ Ap,
                       const float* __restrict__ Bp, const float* __restrict__ Cp,
                       float* __restrict__ P_all, float* __restrict__ logA_all,
                       float* __restrict__ CB_all, float* __restrict__ pooled,
                       int* __restrict__ flags) {
    if (blockIdx.x < 256) {
        // packed[((cg*8+ks)*64+lane)*8+j] = pW[col][k], col=(cg>>2)*64+(cg&3)*16+fr,
        // k=ks*32+fq*8+j
        int i = blockIdx.x * 256 + threadIdx.x;
        int e = i * 8;
        int l = e >> 16;
        int r = e & 65535;
        int cg = r >> 12;
        int ks = (r >> 9) & 7;
        int lane = (r >> 3) & 63;
        int fq = lane >> 4, fr = lane & 15;
        int col = (cg >> 2) * 64 + (cg & 3) * 16 + fr;
        int k = ks * 32 + fq * 8;
        const float* src = pW + l * 65536 + col * 256 + k;
        float4 w0 = *(const float4*)src;
        float4 w1 = *(const float4*)(src + 4);
        float vv[8] = {w0.x, w0.y, w0.z, w0.w, w1.x, w1.y, w1.z, w1.w};
        u16 sh[8], sl[8];
#pragma unroll
        for (int j = 0; j < 8; ++j) split2(vv[j], sh[j], sl[j]);
        u16x8 vh = {sh[0], sh[1], sh[2], sh[3], sh[4], sh[5], sh[6], sh[7]};
        u16x8 vl = {sl[0], sl[1], sl[2], sl[3], sl[4], sl[5], sl[6], sl[7]};
        *(u16x8*)&pWh[e] = vh;
        *(u16x8*)&pWl[e] = vl;
    } else {
        int b = blockIdx.x - 256;
        int c = threadIdx.x;
        float A0 = 1.f / (1.f + expf(-Ap[c]));
        float iw = inW[c], ib = inb[c];
        const float* xb = x + b * LSEQ;
        float pw = 1.f, acc = 0.f;
        for (int t = 0; t <= EMAX; ++t) {
            acc += (xb[t] * iw + ib) * pw;
            pw *= A0;
        }
        P_all[b * DM + c] = acc;
        for (int l = 1; l < NLAYER; ++l) P_all[l * BATCH * DM + b * DM + c] = 0.f;
        for (int e = 0; e < 4; ++e) pooled[e * BATCH * DM + b * DM + c] = 0.f;
        if (b == 0) {
            for (int l = 0; l < NLAYER; ++l) {
                float Al = 1.f / (1.f + expf(-Ap[l * DM + c]));
                logA_all[l * DM + c] = logf(Al);
                CB_all[l * DM + c]   = Bp[l * DM + c] * Cp[l * DM + c];
            }
            if (c < NLAYER * BATCH) flags[c] = 0;
        }
    }
}

// ---------------- persistent-tile fused kernel: 32 rows through all 8 layers ----------------
// 512 blocks (2/CU), 256 thr = 4 waves (wave wn = 64-col slice; m=2 row halves).
// No hT: residual lives in hreg; next layer's A staged by the epilogue itself (fused gelu).
__global__ __launch_bounds__(256, 2) void k_fused(
    const float* __restrict__ x, const float* __restrict__ inW,
    const float* __restrict__ inb,
    const u16* __restrict__ pWh, const u16* __restrict__ pWl,
    const float* __restrict__ Dp_all, const float* __restrict__ pb_all,
    const float* __restrict__ lng_all, const float* __restrict__ lnb_all,
    const float* __restrict__ logA_all, const float* __restrict__ CB_all,
    float* __restrict__ P_all, float* __restrict__ pooled,
    int* __restrict__ flags)
{
    __shared__ __align__(16) char smem[SMEM_SZ];

    int tid  = threadIdx.x;
    int lane = tid & 63;
    int wn   = tid >> 6;            // 0..3 col slice
    int fr   = lane & 15;
    int fq   = lane >> 4;

    int b    = blockIdx.x >> 6;
    int blk  = blockIdx.x & 63;
    int brow = b * LSEQ + blk * BM;
    bool isTail = (blk >= TAILB);
    bool isProd = (blk < NPROD);

    int cols[4];
#pragma unroll
    for (int n = 0; n < 4; ++n) cols[n] = wn * 64 + n * 16 + fr;

    float hreg[2][4][4];                 // h / o for owned (m,n,r)

    // ---- l=0 init: h from x in registers; stage g0 (with tail term) into Ah/Al ----
    {
        float wiv[4], biv[4], D0v[4];
#pragma unroll
        for (int n = 0; n < 4; ++n) {
            wiv[n] = inW[cols[n]];
            biv[n] = inb[cols[n]];
            D0v[n] = Dp_all[cols[n]];
        }
        float la0[4], cb0[4], P0[4];
        if (isTail) {
#pragma unroll
            for (int n = 0; n < 4; ++n) {
                la0[n] = logA_all[cols[n]];
                cb0[n] = CB_all[cols[n]];
                P0[n]  = P_all[b * DM + cols[n]];
            }
        }
#pragma unroll
        for (int m = 0; m < 2; ++m)
#pragma unroll
            for (int r = 0; r < 4; ++r) {
                int row = m * 16 + fq * 4 + r;
                float xv = x[brow + row];
                int u = (LSEQ - 1) - ((brow + row) & (LSEQ - 1));
                bool tl = isTail && (u <= EMAX);
                float uf = (float)u;
#pragma unroll
                for (int n = 0; n < 4; ++n) {
                    float h0 = fmaf(xv, wiv[n], biv[n]);
                    hreg[m][n][r] = h0;
                    float v = D0v[n] * h0;
                    if (tl) v += cb0[n] * __expf(uf * la0[n]) * P0[n];
                    u16 hi, lo;
                    split2(gelu_fast(v), hi, lo);
                    writeA(smem, row, cols[n], hi, lo);
                }
            }
    }
    __syncthreads();

    for (int l = 0; l < NLAYER; ++l) {
        // ---- MFMA: A from LDS, B from packed global (L2-hot), depth-2 prefetch ----
        f32x4 acc[2][4];
#pragma unroll
        for (int m = 0; m < 2; ++m)
#pragma unroll
            for (int n = 0; n < 4; ++n) acc[m][n] = (f32x4){0.f, 0.f, 0.f, 0.f};

        const u16* bhp = pWh + (size_t)l * 65536 + wn * 16384 + lane * 8;
        const u16* blp = pWl + (size_t)l * 65536 + wn * 16384 + lane * 8;

        V8 bhd[3][4], bld[3][4];
#pragma unroll
        for (int n = 0; n < 4; ++n) {
            bhd[0][n].u = *(const u16x8*)&bhp[n * 4096];
            bld[0][n].u = *(const u16x8*)&blp[n * 4096];
            bhd[1][n].u = *(const u16x8*)&bhp[n * 4096 + 512];
            bld[1][n].u = *(const u16x8*)&blp[n * 4096 + 512];
        }
#pragma unroll
        for (int ks = 0; ks < 8; ++ks) {
            int cur = ks % 3;
            if (ks < 6) {
                int nx2 = (ks + 2) % 3;
#pragma unroll
                for (int n = 0; n < 4; ++n) {
                    bhd[nx2][n].u = *(const u16x8*)&bhp[n * 4096 + (ks + 2) * 512];
                    bld[nx2][n].u = *(const u16x8*)&blp[n * 4096 + (ks + 2) * 512];
                }
            }
            V8 ah[2], al[2];
#pragma unroll
            for (int m = 0; m < 2; ++m) {
                int row = m * 16 + fr;
                int aby = row * 512 + (((ks * 4 + fq) ^ (row & 7)) << 4);
                ah[m].u = *(const u16x8*)(smem + aby);
                al[m].u = *(const u16x8*)(smem + AL_OFF + aby);
            }
#pragma unroll
            for (int m = 0; m < 2; ++m)
#pragma unroll
                for (int n = 0; n < 4; ++n) {
                    acc[m][n] = __builtin_amdgcn_mfma_f32_16x16x32_bf16(ah[m].b, bhd[cur][n].b, acc[m][n], 0, 0, 0);
                    acc[m][n] = __builtin_amdgcn_mfma_f32_16x16x32_bf16(ah[m].b, bld[cur][n].b, acc[m][n], 0, 0, 0);
                    acc[m][n] = __builtin_amdgcn_mfma_f32_16x16x32_bf16(al[m].b, bhd[cur][n].b, acc[m][n], 0, 0, 0);
                }
        }

        // ---- p1: y = h + out2 + pb; row sums; cross-wave reduce ----
        float pbv[4], lgv[4], lbv[4];
#pragma unroll
        for (int n = 0; n < 4; ++n) {
            pbv[n] = pb_all[l * DM + cols[n]];
            lgv[n] = lng_all[l * DM + cols[n]];
            lbv[n] = lnb_all[l * DM + cols[n]];
        }
        float s[2][4], ss[2][4];
#pragma unroll
        for (int m = 0; m < 2; ++m)
#pragma unroll
            for (int r = 0; r < 4; ++r) {
                float sy = 0.f, sy2 = 0.f;
#pragma unroll
                for (int n = 0; n < 4; ++n) {
                    float y = hreg[m][n][r] + acc[m][n][r] + pbv[n];
                    acc[m][n][r] = y;
                    sy += y; sy2 += y * y;
                }
                s[m][r] = sy; ss[m][r] = sy2;
            }
#pragma unroll
        for (int m = 0; m < 2; ++m)
#pragma unroll
            for (int r = 0; r < 4; ++r)
#pragma unroll
                for (int msk = 1; msk < 16; msk <<= 1) {
                    s[m][r]  += __shfl_xor(s[m][r],  msk);
                    ss[m][r] += __shfl_xor(ss[m][r], msk);
                }
        if (fr == 0) {
#pragma unroll
            for (int m = 0; m < 2; ++m)
#pragma unroll
                for (int r = 0; r < 4; ++r) {
                    int row = m * 16 + fq * 4 + r;
                    *(float*)(smem + RED_OFF + (row * 10 + wn * 2)     * 4) = s[m][r];
                    *(float*)(smem + RED_OFF + (row * 10 + wn * 2 + 1) * 4) = ss[m][r];
                }
        }
        __syncthreads();   // bar B: red ready (also: all MFMA A-reads done)

        // ---- p2: LN -> o; hreg=o; fused next-layer g staging; pooled; P_next ----
        float mean[2][4], rstd[2][4];
#pragma unroll
        for (int m = 0; m < 2; ++m)
#pragma unroll
            for (int r = 0; r < 4; ++r) {
                int row = m * 16 + fq * 4 + r;
                float st = 0.f, sst = 0.f;
#pragma unroll
                for (int w = 0; w < 4; ++w) {
                    st  += *(const float*)(smem + RED_OFF + (row * 10 + w * 2)     * 4);
                    sst += *(const float*)(smem + RED_OFF + (row * 10 + w * 2 + 1) * 4);
                }
                float mu = st * (1.f / 256.f);
                float var = sst * (1.f / 256.f) - mu * mu;
                mean[m][r] = mu;
                rstd[m][r] = rsqrtf(var + LN_EPS);
            }
        int slot = (l == 1) ? 0 : (l == 3) ? 1 : (l == 5) ? 2 : (l == 7) ? 3 : -1;
        bool last = (l == NLAYER - 1);
        bool prod = !last && isProd;
        float Dnv[4], lanv[4];
        if (!last) {
#pragma unroll
            for (int n = 0; n < 4; ++n) Dnv[n] = Dp_all[(l + 1) * DM + cols[n]];
        }
        if (prod) {
#pragma unroll
            for (int n = 0; n < 4; ++n) lanv[n] = logA_all[(l + 1) * DM + cols[n]];
        }
        float cs[4] = {0.f, 0.f, 0.f, 0.f};
        float pc[4] = {0.f, 0.f, 0.f, 0.f};
#pragma unroll
        for (int m = 0; m < 2; ++m)
#pragma unroll
            for (int r = 0; r < 4; ++r) {
                int row  = m * 16 + fq * 4 + r;
                int trow = blk * BM + row;
#pragma unroll
                for (int n = 0; n < 4; ++n) {
                    float o = (acc[m][n][r] - mean[m][r]) * rstd[m][r] * lgv[n] + lbv[n];
                    hreg[m][n][r] = o;
                    if (!last) {
                        u16 hi, lo;
                        split2(gelu_fast(Dnv[n] * o), hi, lo);
                        writeA(smem, row, cols[n], hi, lo);
                    }
                    if (slot >= 0) cs[n] += o;
                    if (prod && trow <= EMAX) pc[n] += o * __expf((float)trow * lanv[n]);
                }
            }
        if (slot >= 0) {
#pragma unroll
            for (int n = 0; n < 4; ++n) {
                cs[n] += __shfl_xor(cs[n], 16);
                cs[n] += __shfl_xor(cs[n], 32);
            }
            if (lane < 16) {
#pragma unroll
                for (int n = 0; n < 4; ++n)
                    atomicAdd(&pooled[slot * (BATCH * DM) + b * DM + wn * 64 + n * 16 + lane], cs[n]);
            }
        }
        if (prod) {
#pragma unroll
            for (int n = 0; n < 4; ++n) {
                pc[n] += __shfl_xor(pc[n], 16);
                pc[n] += __shfl_xor(pc[n], 32);
            }
            if (lane < 16) {
#pragma unroll
                for (int n = 0; n < 4; ++n)
                    atomicAdd(&P_all[(size_t)(l + 1) * BATCH * DM + b * DM + wn * 64 + n * 16 + lane], pc[n]);
            }
        }
        __syncthreads();   // bar C: Ah/Al(l+1) staged; P atomics drained

        if (!last) {
            if (prod && tid == 0)
                __hip_atomic_fetch_add(&flags[(l + 1) * BATCH + b], 1,
                                       __ATOMIC_RELEASE, __HIP_MEMORY_SCOPE_AGENT);
            if (isTail) {
                // wait for P[l+1], then fix tail rows' A fragments in-place
                if (tid == 0) {
                    while (__hip_atomic_load(&flags[(l + 1) * BATCH + b], __ATOMIC_ACQUIRE,
                                             __HIP_MEMORY_SCOPE_AGENT) < NPROD)
                        __builtin_amdgcn_s_sleep(2);
                }
                __syncthreads();
                float lanx[4], cbnx[4], Pnx[4];
#pragma unroll
                for (int n = 0; n < 4; ++n) {
                    lanx[n] = logA_all[(l + 1) * DM + cols[n]];
                    cbnx[n] = CB_all[(l + 1) * DM + cols[n]];
                    Pnx[n]  = __hip_atomic_load(
                        &P_all[(size_t)(l + 1) * BATCH * DM + b * DM + cols[n]],
                        __ATOMIC_RELAXED, __HIP_MEMORY_SCOPE_AGENT);
                }
#pragma unroll
                for (int m = 0; m < 2; ++m)
#pragma unroll
                    for (int r = 0; r < 4; ++r) {
                        int row = m * 16 + fq * 4 + r;
                        int u = (LSEQ - 1) - ((brow + row) & (LSEQ - 1));
                        if (u <= EMAX) {
                            float uf = (float)u;
#pragma unroll
                            for (int n = 0; n < 4; ++n) {
                                float v = Dnv[n] * hreg[m][n][r] +
                                          cbnx[n] * __expf(uf * lanx[n]) * Pnx[n];
                                u16 hi, lo;
                                split2(gelu_fast(v), hi, lo);
                                writeA(smem, row, cols[n], hi, lo);
                            }
                        }
                    }
                __syncthreads();
            }
        }
    }
}

// ---------------- head ----------------
__global__ void k_head(const float* __restrict__ pooled, const float* __restrict__ hW,
                       const float* __restrict__ hb, float* __restrict__ out) {
    int tid = threadIdx.x;
    if (tid >= 96) return;
    int e = tid / 24;
    int r = tid % 24;
    int b = r / 3;
    int n = r % 3;
    const float* pv = &pooled[e * (BATCH * DM) + b * DM];
    const float* wv = &hW[(e * 3 + n) * DM];
    float acc = 0.f;
    for (int c = 0; c < DM; ++c) acc += pv[c] * wv[c];
    out[e * 24 + b * 3 + n] = acc * (1.f / (float)LSEQ) + hb[e * 3 + n];
}

extern "C" void kernel_launch(void* const* d_in, const int* in_sizes, int n_in,
                              void* d_out, int out_size, void* d_ws, size_t ws_size,
                              hipStream_t stream) {
    const float* x   = (const float*)d_in[0];
    const float* inW = (const float*)d_in[1];
    const float* inb = (const float*)d_in[2];
    const float* Ap  = (const float*)d_in[3];
    const float* Bp  = (const float*)d_in[4];
    const float* Cp  = (const float*)d_in[5];
    const float* Dp  = (const float*)d_in[6];
    const float* pW  = (const float*)d_in[7];
    const float* pb  = (const float*)d_in[8];
    const float* lng = (const float*)d_in[9];
    const float* lnb = (const float*)d_in[10];
    const float* hW  = (const float*)d_in[11];
    const float* hb  = (const float*)d_in[12];
    float* out = (float*)d_out;

    float* ws = (float*)d_ws;
    float* P_all    = ws;                            // 16384
    float* logA_all = P_all + NLAYER * BATCH * DM;   // 2048
    float* CB_all   = logA_all + NLAYER * DM;        // 2048
    float* pooled   = CB_all + NLAYER * DM;          // 8192
    u16* pWh        = (u16*)(pooled + 4 * BATCH * DM);   // 524288 u16
    u16* pWl        = pWh + NLAYER * DM * DM;            // 524288 u16
    int* flags      = (int*)(pWl + NLAYER * DM * DM);    // 64 ints

    k_prep<<<264, 256, 0, stream>>>(pW, pWh, pWl, x, inW, inb, Ap, Bp, Cp,
                                    P_all, logA_all, CB_all, pooled, flags);
    k_fused<<<BATCH * BLKS, 256, 0, stream>>>(
        x, inW, inb, pWh, pWl, Dp, pb, lng, lnb,
        logA_all, CB_all, P_all, pooled, flags);
    k_head<<<1, 128, 0, stream>>>(pooled, hW, hb, out);
}